// Round 14
// baseline (424.068 us; speedup 1.0000x reference)
//
#include <hip/hip_runtime.h>
#include <hip/hip_bf16.h>

typedef __bf16 bf16x8 __attribute__((ext_vector_type(8)));
typedef float f32x4 __attribute__((ext_vector_type(4)));
typedef unsigned short u16x8 __attribute__((ext_vector_type(8)));
typedef unsigned short u16x4 __attribute__((ext_vector_type(4)));

#define DEV static __device__ __forceinline__

DEV unsigned short f2bf(float f) {
    unsigned u = __builtin_bit_cast(unsigned, f);
    u += 0x7fffu + ((u >> 16) & 1u);   // round-to-nearest-even
    return (unsigned short)(u >> 16);
}
DEV float bf2f(unsigned short h) {
    unsigned u = ((unsigned)h) << 16;
    return __builtin_bit_cast(float, u);
}

DEV void gl2lds16(const void* g, void* l) {
    __builtin_amdgcn_global_load_lds(
        (const __attribute__((address_space(1))) void*)g,
        (__attribute__((address_space(3))) void*)l, 16, 0, 0);
}

#define WAITV(N) asm volatile("s_waitcnt vmcnt(" #N ")" ::: "memory")
#define SBAR()   asm volatile("s_barrier" ::: "memory")

// ===========================================================================
// gemm128d (round-8 "v2" engine — best measured: W13 117 µs):
// 128x256 tile, BK=64, deep pipeline, 3 LDS buffers (144 KiB), 2-tile
// lookahead, 32-MFMA cluster, ds_read of t+1 after the barrier.
// Swizzle: phys_byte = logical ^ ((row&7)<<4), both-sides. Bank-conflict 0.
// 8 waves 2Mx4N, wave 64x64, acc[4][4]. Weights pre-converted to bf16 BT.
// EPI 1: split-K=2 fp32 partials.  EPI 2: fused SwiGLU -> [M][N/2] bf16.
// EPI 3: split-K=2 + unsafeAtomicAdd into fp32 outP (holds residual h).
// EPI 4: QKV epilogue — RoPE on q/k cols (<4096), V transposed to vT.
// ===========================================================================
#define STAGE128D(KT, BUF)                                                    \
    _Pragma("unroll")                                                         \
    for (int sl = 0; sl < 3; ++sl) {                                          \
        const unsigned short* sbase = (sl == 0)                               \
            ? A  + (size_t)bm * K                                             \
            : BT + (size_t)(bn + (sl - 1) * 128) * K;                         \
        _Pragma("unroll")                                                     \
        for (int j = 0; j < 2; ++j) {                                         \
            const unsigned short* g = sbase + (size_t)(srow + j * 64) * K     \
                                      + koff + (KT) * 64 + lc;                \
            gl2lds16(g, &lds[BUF][sl][wave * 512 + j * 4096]);                \
        }                                                                     \
    }

#define DSREAD128(BUF)                                                        \
    {                                                                         \
        const char* Ab = (const char*)&lds[BUF][0][0];                        \
        const char* Bb = (const char*)&lds[BUF][1 + (wn >> 1)][0];            \
        _Pragma("unroll")                                                     \
        for (int m4 = 0; m4 < 4; ++m4)                                        \
            _Pragma("unroll")                                                 \
            for (int kk = 0; kk < 2; ++kk)                                    \
                a_[m4][kk] = *(const bf16x8*)(Ab +                            \
                    (wm * 64 + m4 * 16 + lr) * 128 +                          \
                    ((kk * 64 + lg * 16) ^ xsw));                             \
        _Pragma("unroll")                                                     \
        for (int n2 = 0; n2 < 4; ++n2)                                        \
            _Pragma("unroll")                                                 \
            for (int kk = 0; kk < 2; ++kk)                                    \
                b_[n2][kk] = *(const bf16x8*)(Bb +                            \
                    ((wn & 1) * 64 + n2 * 16 + lr) * 128 +                    \
                    ((kk * 64 + lg * 16) ^ xsw));                             \
    }

#define MFMA128                                                               \
    __builtin_amdgcn_s_setprio(1);                                            \
    _Pragma("unroll")                                                         \
    for (int m4 = 0; m4 < 4; ++m4)                                            \
        _Pragma("unroll")                                                     \
        for (int n2 = 0; n2 < 4; ++n2)                                        \
            _Pragma("unroll")                                                 \
            for (int kk = 0; kk < 2; ++kk)                                    \
                acc[m4][n2] = __builtin_amdgcn_mfma_f32_16x16x32_bf16(        \
                    a_[m4][kk], b_[n2][kk], acc[m4][n2], 0, 0, 0);            \
    __builtin_amdgcn_s_setprio(0);

template <int EPI>
__global__ __launch_bounds__(512, 2)
void gemm128d(const unsigned short* __restrict__ A,
              const unsigned short* __restrict__ BT,
              unsigned short* __restrict__ outB,
              float* __restrict__ outP,
              int M, int N, int K,
              const float* __restrict__ cs, const float* __restrict__ sn,
              unsigned short* __restrict__ vT)
{
    __shared__ alignas(16) unsigned short lds[3][3][8192];   // 144 KiB
    const int tid  = threadIdx.x;
    const int lane = tid & 63;
    const int wave = tid >> 6;
    const int wm = wave >> 2;
    const int wn = wave & 3;
    const int lr = lane & 15;
    const int lg = lane >> 4;
    const int gy  = gridDim.y;
    const int lin = blockIdx.y * gridDim.x + blockIdx.x;
    const int cpx = (gridDim.x * gy) >> 3;   // grid (x*y) % 8 == 0 required
    const int swz = (lin & 7) * cpx + (lin >> 3);
    const int bm = (swz % gy) * 128;
    const int bn = (swz / gy) * 256;
    const int xsw  = (lr & 7) << 4;
    const int srow = tid >> 3;
    const int lc   = ((tid & 7) ^ (srow & 7)) * 8;
    int koff, NT;
    if constexpr (EPI == 1 || EPI == 3) {
        const int Kh = K >> 1; koff = blockIdx.z * Kh; NT = Kh >> 6;
    } else {
        koff = 0; NT = K >> 6;
    }

    f32x4 acc[4][4] = {};
    bf16x8 a_[4][2], b_[4][2];

    // prologue: stage T0,T1; wait T0; read T0 fragments
    STAGE128D(0, 0);
    STAGE128D(1, 1);
    WAITV(6); SBAR();
    DSREAD128(0);

    int bc = 0;
    for (int kt = 0; kt < NT - 2; ++kt) {
        const int nb = (bc == 0) ? 2 : bc - 1;     // (bc+2)%3
        STAGE128D(kt + 2, nb);
        MFMA128;                                   // tile kt (frags in regs)
        WAITV(6); SBAR();                          // T(kt+1) landed everywhere
        const int rb = (bc == 2) ? 0 : bc + 1;     // (bc+1)%3
        DSREAD128(rb);                             // frags tile kt+1
        bc = rb;
    }
    // kt = NT-2
    MFMA128;
    WAITV(0); SBAR();                              // T(NT-1) landed
    {
        const int rb = (bc == 2) ? 0 : bc + 1;
        DSREAD128(rb);
    }
    // kt = NT-1
    MFMA128;

#pragma unroll
    for (int m4 = 0; m4 < 4; ++m4) {
        const int row = bm + wm * 64 + m4 * 16 + lg * 4;
#pragma unroll
        for (int n2 = 0; n2 < 4; ++n2) {
            const int col = bn + wn * 64 + n2 * 16 + lr;
            if constexpr (EPI == 4) {
                if (bn >= 4096) {
                    // V: write transposed vT[d][s] (8B store, rows contiguous)
                    u16x4 o;
#pragma unroll
                    for (int r = 0; r < 4; ++r) o[r] = f2bf(acc[m4][n2][r]);
                    *(u16x4*)(vT + (size_t)(col - 4096) * 2048 + row) = o;
                } else {
                    // Q/K: RoPE via lane-pair shuffle
#pragma unroll
                    for (int r = 0; r < 4; ++r) {
                        const float v  = acc[m4][n2][r];
                        const float vo = __shfl_xor(v, 1);
                        const int rr = row + r;
                        const int i0 = (col & 127) >> 1;
                        const float c = cs[rr * 64 + i0];
                        const float s = sn[rr * 64 + i0];
                        const float o = (lr & 1) ? (vo * s + v * c)   // im' = re*s+im*c
                                                 : (v * c - vo * s);  // re' = re*c-im*s
                        outB[(size_t)rr * N + col] = f2bf(o);
                    }
                }
            } else {
#pragma unroll
                for (int r = 0; r < 4; ++r) {
                    if constexpr (EPI == 1) {
                        outP[(size_t)blockIdx.z * M * N + (size_t)(row + r) * N + col] = acc[m4][n2][r];
                    } else if constexpr (EPI == 3) {
                        unsafeAtomicAdd(&outP[(size_t)(row + r) * N + col], acc[m4][n2][r]);
                    } else {   // EPI == 2: fused SwiGLU
                        const float v  = acc[m4][n2][r];
                        const float vo = __shfl_xor(v, 1);
                        const float x1 = (lr & 1) ? vo : v;
                        const float x3 = (lr & 1) ? v : vo;
                        const float g  = x1 / (1.0f + __expf(-x1)) * x3;
                        if (!(lr & 1))
                            outB[(size_t)(row + r) * (N >> 1) + (col >> 1)] = f2bf(g);
                    }
                }
            }
        }
    }
}

// h = res + p[0] + p[1]; hout = h; nout = rmsnorm(h)*w  — one block per row.
__global__ __launch_bounds__(256)
void reduce2_norm(const float* __restrict__ res, const float* __restrict__ p,
                  const float* __restrict__ w, float* __restrict__ hout,
                  unsigned short* __restrict__ nout)
{
    const int row = blockIdx.x, tid = threadIdx.x;
    const float4* r4 = (const float4*)(res + (size_t)row * 2048);
    const float4* a4 = (const float4*)(p   + (size_t)row * 2048);
    const float4* b4 = (const float4*)(p + (size_t)2048 * 2048 + (size_t)row * 2048);
    float4* h4 = (float4*)(hout + (size_t)row * 2048);
    float4 h[2];
    float ss = 0.f;
#pragma unroll
    for (int i = 0; i < 2; ++i) {
        const int idx = i * 256 + tid;
        const float4 r = r4[idx], a = a4[idx], b = b4[idx];
        float4 v = make_float4(r.x + a.x + b.x, r.y + a.y + b.y,
                               r.z + a.z + b.z, r.w + a.w + b.w);
        h[i] = v; h4[idx] = v;
        ss += v.x * v.x + v.y * v.y + v.z * v.z + v.w * v.w;
    }
#pragma unroll
    for (int off = 32; off; off >>= 1) ss += __shfl_xor(ss, off);
    __shared__ float red[4];
    if ((tid & 63) == 0) red[tid >> 6] = ss;
    __syncthreads();
    const float tot = red[0] + red[1] + red[2] + red[3];
    const float sc = rsqrtf(tot * (1.0f / 2048.0f) + 1e-5f);
#pragma unroll
    for (int i = 0; i < 2; ++i) {
        const int idx = i * 256 + tid;
        const float4 wv = ((const float4*)w)[idx];
        u16x4 o;
        o[0] = f2bf(h[i].x * sc * wv.x); o[1] = f2bf(h[i].y * sc * wv.y);
        o[2] = f2bf(h[i].z * sc * wv.z); o[3] = f2bf(h[i].w * sc * wv.w);
        *(u16x4*)(nout + (size_t)row * 2048 + idx * 4) = o;
    }
}

// ---------------------------------------------------------------------------
// RMSNorm: fp32 in [2048][2048] -> bf16 out, weight fp32. One block per row.
// ---------------------------------------------------------------------------
__global__ __launch_bounds__(256)
void rmsnorm_kernel(const float* __restrict__ x, const float* __restrict__ w,
                    unsigned short* __restrict__ out)
{
    const int row = blockIdx.x;
    const int tid = threadIdx.x;
    const float* xr = x + (size_t)row * 2048;
    const float4 a = *reinterpret_cast<const float4*>(xr + tid * 8);
    const float4 b = *reinterpret_cast<const float4*>(xr + tid * 8 + 4);
    float ss = a.x * a.x + a.y * a.y + a.z * a.z + a.w * a.w
             + b.x * b.x + b.y * b.y + b.z * b.z + b.w * b.w;
#pragma unroll
    for (int off = 32; off; off >>= 1) ss += __shfl_xor(ss, off);
    __shared__ float red[4];
    if ((tid & 63) == 0) red[tid >> 6] = ss;
    __syncthreads();
    const float tot = red[0] + red[1] + red[2] + red[3];
    const float sc = rsqrtf(tot * (1.0f / 2048.0f) + 1e-5f);
    const float4 wa = *reinterpret_cast<const float4*>(w + tid * 8);
    const float4 wb = *reinterpret_cast<const float4*>(w + tid * 8 + 4);
    u16x8 o;
    o[0] = f2bf(a.x * sc * wa.x); o[1] = f2bf(a.y * sc * wa.y);
    o[2] = f2bf(a.z * sc * wa.z); o[3] = f2bf(a.w * sc * wa.w);
    o[4] = f2bf(b.x * sc * wb.x); o[5] = f2bf(b.y * sc * wb.y);
    o[6] = f2bf(b.z * sc * wb.z); o[7] = f2bf(b.w * sc * wb.w);
    *reinterpret_cast<u16x8*>(out + (size_t)row * 2048 + tid * 8) = o;
}

// ---------------------------------------------------------------------------
// Weight convert + transpose (fp32 [K][N] -> bf16 wT[rmul*n+radd][K]).
// ---------------------------------------------------------------------------
DEV void convT_half(const float* __restrict__ w, unsigned short* __restrict__ wT,
                    int K, int N, int rmul, int radd, int bk, int bn,
                    int tid, unsigned short (*t)[66])
{
    const int r = tid >> 4, c4 = (tid & 15) * 4;
#pragma unroll
    for (int i = 0; i < 4; ++i) {
        const int row = r + i * 16;
        const float4 v = *reinterpret_cast<const float4*>(w + (size_t)(bk + row) * N + bn + c4);
        t[row][c4 + 0] = f2bf(v.x); t[row][c4 + 1] = f2bf(v.y);
        t[row][c4 + 2] = f2bf(v.z); t[row][c4 + 3] = f2bf(v.w);
    }
    __syncthreads();
#pragma unroll
    for (int i = 0; i < 4; ++i) {
        const int n = r + i * 16;
        u16x4 o;
#pragma unroll
        for (int e = 0; e < 4; ++e) o[e] = t[c4 + e][n];
        *reinterpret_cast<u16x4*>(wT + (size_t)(rmul * (bn + n) + radd) * K + bk + c4) = o;
    }
}

// wq/wk/wv (needed before QKV) — standalone dispatch
__global__ __launch_bounds__(256)
void convT3_kernel(const float* __restrict__ w0, const float* __restrict__ w1,
                   const float* __restrict__ w2v, unsigned short* __restrict__ wT)
{
    __shared__ unsigned short t[64][66];
    const int z = blockIdx.z;
    const float* w = (z == 0) ? w0 : (z == 1) ? w1 : w2v;
    convT_half(w, wT + (size_t)z * 2048 * 2048, 2048, 2048, 1, 0,
               blockIdx.y * 64, blockIdx.x * 64, threadIdx.x, t);
}

// tile decode for mega convT: t2 in [0, 9472)
DEV void ct_decode(int t2,
                   const float* wo, const float* w1, const float* w3,
                   const float* w2,
                   unsigned short* woT, unsigned short* w13T, unsigned short* w2T,
                   const float*& w, unsigned short*& wT,
                   int& K, int& N, int& rmul, int& radd, int& bk, int& bn)
{
    if (t2 < 1024) {
        w = wo; wT = woT; K = 2048; N = 2048; rmul = 1; radd = 0;
        bk = (t2 >> 5) * 64; bn = (t2 & 31) * 64;
    } else if (t2 < 6656) {
        const int u = t2 - 1024;
        const int z = u / 2816, rm = u % 2816;
        w = z ? w3 : w1; wT = w13T; K = 2048; N = 5632; rmul = 2; radd = z;
        bk = (rm / 88) * 64; bn = (rm % 88) * 64;
    } else {
        const int u = t2 - 6656;
        w = w2; wT = w2T; K = 5632; N = 2048; rmul = 1; radd = 0;
        bk = (u / 32) * 64; bn = (u % 32) * 64;
    }
}

// ---------------------------------------------------------------------------
// MEGA kernel: blocks 0..255 = causal flash attention (paired q-tiles);
// blocks 256..767 = convT grid-stride workers for wo / {w1,w3} / w2 —
// back-fill idle CUs as flash blocks finish. Each convT block: 2 halves
// (256 thr each), 10 fixed iterations over tiles gid, gid+1024, ... with
// register double-buffer (issue next tile's loads before transposing the
// current one). Unconditional barriers -> no divergent-barrier hazard.
// convT transpose buffers ALIAS Ks (convT blocks never run flash code).
// LDS = 90112 B.
// ---------------------------------------------------------------------------
__global__ __launch_bounds__(512)
void flash_mega(const unsigned short* __restrict__ q,
                const unsigned short* __restrict__ k,
                const unsigned short* __restrict__ vT,
                unsigned short* __restrict__ attn,
                const float* __restrict__ wo, const float* __restrict__ w1,
                const float* __restrict__ w3, const float* __restrict__ w2,
                unsigned short* __restrict__ woT,
                unsigned short* __restrict__ w13T,
                unsigned short* __restrict__ w2T)
{
    __shared__ alignas(16) unsigned short Ks[2][64][136];  // [buf][kv][hd]
    __shared__ alignas(16) unsigned short Vs[2][128][72];  // [buf][hd][kv]
    __shared__ alignas(16) unsigned short Ps[8][16][72];   // per-wave P

    const int bid = blockIdx.x;
    const int tid = threadIdx.x;

    if (bid >= 256) {   // ---- convT grid-stride role ----
        const int half = tid >> 8;
        const int t256 = tid & 255;
        const int gid  = (bid - 256) * 2 + half;            // 0..1023
        const int r = t256 >> 4, c4 = (t256 & 15) * 4;
        // transpose buffer aliases Ks storage (2 x 64x66 u16 = 16.5 KB < 34 KB)
        unsigned short (*tb)[66] =
            (unsigned short (*)[66])(&Ks[0][0][0] + half * 64 * 66);
        const int TOT = 9472;

        float4 cur[4], nxt[4];
        const float* wC; unsigned short* wTC;
        int KC, NC, rmC, raC, bkC, bnC;
        int t2 = gid;
        bool act = (t2 < TOT);
        if (act) {
            ct_decode(t2, wo, w1, w3, w2, woT, w13T, w2T,
                      wC, wTC, KC, NC, rmC, raC, bkC, bnC);
#pragma unroll
            for (int i = 0; i < 4; ++i)
                cur[i] = *(const float4*)(wC + (size_t)(bkC + r + i * 16) * NC + bnC + c4);
        }
#pragma unroll 1
        for (int it = 0; it < 10; ++it) {
            const int t2n = t2 + 1024;
            const bool actn = (t2n < TOT);
            const float* wN; unsigned short* wTN;
            int KN, NN, rmN, raN, bkN, bnN;
            if (actn) {   // issue next tile's loads early
                ct_decode(t2n, wo, w1, w3, w2, woT, w13T, w2T,
                          wN, wTN, KN, NN, rmN, raN, bkN, bnN);
#pragma unroll
                for (int i = 0; i < 4; ++i)
                    nxt[i] = *(const float4*)(wN + (size_t)(bkN + r + i * 16) * NN + bnN + c4);
            }
            if (act) {    // transpose current tile through LDS
#pragma unroll
                for (int i = 0; i < 4; ++i) {
                    const int row = r + i * 16;
                    tb[row][c4 + 0] = f2bf(cur[i].x);
                    tb[row][c4 + 1] = f2bf(cur[i].y);
                    tb[row][c4 + 2] = f2bf(cur[i].z);
                    tb[row][c4 + 3] = f2bf(cur[i].w);
                }
            }
            __syncthreads();
            if (act) {
#pragma unroll
                for (int i = 0; i < 4; ++i) {
                    const int n = r + i * 16;
                    u16x4 o;
#pragma unroll
                    for (int e = 0; e < 4; ++e) o[e] = tb[c4 + e][n];
                    *reinterpret_cast<u16x4*>(
                        wTC + (size_t)(rmC * (bnC + n) + raC) * KC + bkC + c4) = o;
                }
            }
            __syncthreads();
            // rotate
            t2 = t2n; act = actn;
            if (actn) {
                wC = wN; wTC = wTN; KC = KN; NC = NN;
                rmC = rmN; raC = raN; bkC = bkN; bnC = bnN;
#pragma unroll
                for (int i = 0; i < 4; ++i) cur[i] = nxt[i];
            }
        }
        return;
    }

    // ---- flash attention role ----
    const int hh = bid >> 4;
    const int pi = bid & 15;                // 0..15
    const int lane = tid & 63, wave = tid >> 6;
    const int qt = (wave >> 2) ? (31 - pi) : pi;
    const int lr = lane & 15, lg = lane >> 4;
    const int q0 = qt * 64 + (wave & 3) * 16;
    const int myNT = qt + 1;
    const int NT   = 32 - pi;

    const int kr0 = tid >> 4, kc0 = (tid & 15) * 8;
    const int vr0 = tid >> 3, vc0 = (tid & 7) * 8;

    bf16x8 qf[4];
#pragma unroll
    for (int c = 0; c < 4; ++c)
        qf[c] = *reinterpret_cast<const bf16x8*>(
            q + (size_t)(q0 + lr) * 6144 + hh * 128 + c * 32 + lg * 8);

    f32x4 oacc[8] = {};
    float m_r[4], l_r[4];
#pragma unroll
    for (int r = 0; r < 4; ++r) { m_r[r] = -INFINITY; l_r[r] = 0.0f; }
    const float scale = 0.08838834764831845f;   // 1/sqrt(128)

    u16x8 kreg0, kreg1, vreg0, vreg1;
    auto gload = [&](int kt) {
        const int kv0 = kt * 64;
        kreg0 = *reinterpret_cast<const u16x8*>(k + (size_t)(kv0 + kr0) * 6144 + hh * 128 + kc0);
        kreg1 = *reinterpret_cast<const u16x8*>(k + (size_t)(kv0 + kr0 + 32) * 6144 + hh * 128 + kc0);
        vreg0 = *reinterpret_cast<const u16x8*>(vT + (size_t)(hh * 128 + vr0) * 2048 + kv0 + vc0);
        vreg1 = *reinterpret_cast<const u16x8*>(vT + (size_t)(hh * 128 + vr0 + 64) * 2048 + kv0 + vc0);
    };
    auto lwrite = [&](int buf) {
        *reinterpret_cast<u16x8*>(&Ks[buf][kr0][kc0])      = kreg0;
        *reinterpret_cast<u16x8*>(&Ks[buf][kr0 + 32][kc0]) = kreg1;
        *reinterpret_cast<u16x8*>(&Vs[buf][vr0][vc0])      = vreg0;
        *reinterpret_cast<u16x8*>(&Vs[buf][vr0 + 64][vc0]) = vreg1;
    };

    gload(0); lwrite(0);
    __syncthreads();

    for (int kt = 0; kt < NT; ++kt) {
        const int buf = kt & 1;
        if (kt + 1 < NT) gload(kt + 1);

        if (kt < myNT) {
            const int kv0 = kt * 64;
            const bool masked = (kt == myNT - 1);
            f32x4 s[4] = {};
            __builtin_amdgcn_s_setprio(1);
#pragma unroll
            for (int ct = 0; ct < 4; ++ct)
#pragma unroll
                for (int c = 0; c < 4; ++c) {
                    const bf16x8 kf = *reinterpret_cast<const bf16x8*>(
                        &Ks[buf][ct * 16 + lr][c * 32 + lg * 8]);
                    s[ct] = __builtin_amdgcn_mfma_f32_16x16x32_bf16(qf[c], kf, s[ct], 0, 0, 0);
                }
            __builtin_amdgcn_s_setprio(0);
#pragma unroll
            for (int ct = 0; ct < 4; ++ct)
#pragma unroll
                for (int r = 0; r < 4; ++r) {
                    float v = s[ct][r] * scale;
                    if (masked) {
                        const int kvg = kv0 + ct * 16 + lr;
                        const int qg  = q0 + lg * 4 + r;
                        if (kvg > qg) v = -INFINITY;
                    }
                    s[ct][r] = v;
                }
            float mn[4], alpha[4], rs[4];
#pragma unroll
            for (int r = 0; r < 4; ++r) {
                float v = fmaxf(fmaxf(s[0][r], s[1][r]), fmaxf(s[2][r], s[3][r]));
                v = fmaxf(v, __shfl_xor(v, 1));
                v = fmaxf(v, __shfl_xor(v, 2));
                v = fmaxf(v, __shfl_xor(v, 4));
                v = fmaxf(v, __shfl_xor(v, 8));
                mn[r] = fmaxf(m_r[r], v);
                alpha[r] = __expf(m_r[r] - mn[r]);
                m_r[r] = mn[r];
                rs[r] = 0.0f;
            }
#pragma unroll
            for (int ct = 0; ct < 4; ++ct)
#pragma unroll
                for (int r = 0; r < 4; ++r) {
                    const float p = __expf(s[ct][r] - mn[r]);
                    s[ct][r] = p;
                    rs[r] += p;
                }
#pragma unroll
            for (int r = 0; r < 4; ++r) {
                float t2 = rs[r];
                t2 += __shfl_xor(t2, 1);
                t2 += __shfl_xor(t2, 2);
                t2 += __shfl_xor(t2, 4);
                t2 += __shfl_xor(t2, 8);
                l_r[r] = l_r[r] * alpha[r] + t2;
            }
#pragma unroll
            for (int ot = 0; ot < 8; ++ot)
#pragma unroll
                for (int r = 0; r < 4; ++r) oacc[ot][r] *= alpha[r];

#pragma unroll
            for (int ct = 0; ct < 4; ++ct)
#pragma unroll
                for (int r = 0; r < 4; ++r)
                    Ps[wave][lg * 4 + r][ct * 16 + lr] = f2bf(s[ct][r]);

            __builtin_amdgcn_s_setprio(1);
#pragma unroll
            for (int c2 = 0; c2 < 2; ++c2) {
                const bf16x8 pf = *reinterpret_cast<const bf16x8*>(
                    &Ps[wave][lr][c2 * 32 + lg * 8]);
#pragma unroll
                for (int ot = 0; ot < 8; ++ot) {
                    const bf16x8 vf = *reinterpret_cast<const bf16x8*>(
                        &Vs[buf][ot * 16 + lr][c2 * 32 + lg * 8]);
                    oacc[ot] = __builtin_amdgcn_mfma_f32_16x16x32_bf16(pf, vf, oacc[ot], 0, 0, 0);
                }
            }
            __builtin_amdgcn_s_setprio(0);
        }

        if (kt + 1 < NT) lwrite(buf ^ 1);
        __syncthreads();
    }

#pragma unroll
    for (int ot = 0; ot < 8; ++ot)
#pragma unroll
        for (int r = 0; r < 4; ++r) {
            const float v = oacc[ot][r] / l_r[r];
            attn[(size_t)(q0 + lg * 4 + r) * 2048 + hh * 128 + ot * 16 + lr] = f2bf(v);
        }
}

// ---------------------------------------------------------------------------
extern "C" void kernel_launch(void* const* d_in, const int* in_sizes, int n_in,
                              void* d_out, int out_size, void* d_ws, size_t ws_size,
                              hipStream_t stream)
{
    const float* x    = (const float*)d_in[0];
    const float* fcos = (const float*)d_in[1];
    const float* fsin = (const float*)d_in[2];
    // d_in[3] = mask (causal, hardcoded)
    const float* wq  = (const float*)d_in[4];
    const float* wk  = (const float*)d_in[5];
    const float* wv  = (const float*)d_in[6];
    const float* wo  = (const float*)d_in[7];
    const float* w1  = (const float*)d_in[8];
    const float* w2  = (const float*)d_in[9];
    const float* w3  = (const float*)d_in[10];
    const float* anw = (const float*)d_in[11];
    const float* fnw = (const float*)d_in[12];
    float* out = (float*)d_out;

    char* ws = (char*)d_ws;
    size_t off = 0;
    auto alloc = [&](size_t bytes) { void* p = ws + off; off += bytes; return p; };
    const size_t SZ_DD = (size_t)2048 * 2048 * 2;   // 8 MiB
    const size_t SZ_DF = (size_t)2048 * 5632 * 2;   // 22 MiB

    unsigned short* qkvoT = (unsigned short*)alloc(4 * SZ_DD);  // wq|wk|wv|wo T
    unsigned short* w13T  = (unsigned short*)alloc(2 * SZ_DF);  // interleaved [11264][2048]
    unsigned short* w2T   = (unsigned short*)alloc(SZ_DF);

    // region1 (48 MiB), attn phase: xn[0:8) | qkv[8:32) | vTb[32:40) | ab[40:48)
    // pk (32 MiB fp32 split-K partials for Wo) overlays [0:32) when dead;
    // hn overlays vTb's region [32:40) (vTb dead after flash).
    char* reg1 = (char*)alloc((size_t)48 * 1024 * 1024);
    unsigned short* xn   = (unsigned short*)reg1;
    unsigned short* qkv  = (unsigned short*)(reg1 + SZ_DD);            // [2048][6144]
    unsigned short* vTb  = (unsigned short*)(reg1 + SZ_DD + 3 * SZ_DD);
    unsigned short* ab   = (unsigned short*)(reg1 + SZ_DD + 4 * SZ_DD);
    float*          pk   = (float*)reg1;                               // [2][2048][2048] f32
    unsigned short* hn   = (unsigned short*)(reg1 + 4 * SZ_DD);        // [2048][2048]

    char* reg2 = (char*)alloc(SZ_DF);
    unsigned short* t1 = (unsigned short*)reg2;                        // [2048][5632]

    // wq/wk/wv fp32 -> bf16 transposed (needed by QKV)
    convT3_kernel<<<dim3(32, 32, 3), 256, 0, stream>>>(wq, wk, wv, qkvoT);

    // attention block
    rmsnorm_kernel<<<2048, 256, 0, stream>>>(x, anw, xn);
    // fused QKV + RoPE + V-transpose (384 blocks)
    gemm128d<4><<<dim3(24, 16), 512, 0, stream>>>(xn, qkvoT, qkv, nullptr,
                                                  2048, 6144, 2048, fcos, fsin, vTb);
    // flash attention + back-filled convT for wo / {w1,w3} / w2
    flash_mega<<<768, 512, 0, stream>>>(qkv, qkv + 2048, vTb, ab,
                                        wo, w1, w3, w2,
                                        qkvoT + 3 * (size_t)2048 * 2048, w13T, w2T);
    // Wo split-K=2
    gemm128d<1><<<dim3(8, 16, 2), 512, 0, stream>>>(ab, qkvoT + 3 * (size_t)2048 * 2048,
                                                    nullptr, pk, 2048, 2048, 2048,
                                                    nullptr, nullptr, nullptr);
    // fused: out = x + Wo-partials; hn = rmsnorm(out) * fnw
    reduce2_norm<<<2048, 256, 0, stream>>>(x, pk, fnw, out, hn);

    // FFN block
    // W13 + fused SwiGLU epilogue: t1 = silu(hn@w1) * (hn@w3), 704 blocks
    gemm128d<2><<<dim3(44, 16), 512, 0, stream>>>(hn, w13T, t1, nullptr,
                                                  2048, 11264, 2048,
                                                  nullptr, nullptr, nullptr);
    // W2 split-K=2 with atomic residual add into out (out already holds h)
    gemm128d<3><<<dim3(8, 16, 2), 512, 0, stream>>>(t1, w2T, nullptr, out,
                                                    2048, 2048, 5632,
                                                    nullptr, nullptr, nullptr);
}

// Round 15
// 402.053 us; speedup vs baseline: 1.0548x; 1.0548x over previous
//
#include <hip/hip_runtime.h>
#include <hip/hip_bf16.h>

typedef __bf16 bf16x8 __attribute__((ext_vector_type(8)));
typedef float f32x4 __attribute__((ext_vector_type(4)));
typedef unsigned short u16x8 __attribute__((ext_vector_type(8)));
typedef unsigned short u16x4 __attribute__((ext_vector_type(4)));

#define DEV static __device__ __forceinline__

DEV unsigned short f2bf(float f) {
    unsigned u = __builtin_bit_cast(unsigned, f);
    u += 0x7fffu + ((u >> 16) & 1u);   // round-to-nearest-even
    return (unsigned short)(u >> 16);
}
DEV float bf2f(unsigned short h) {
    unsigned u = ((unsigned)h) << 16;
    return __builtin_bit_cast(float, u);
}

DEV void gl2lds16(const void* g, void* l) {
    __builtin_amdgcn_global_load_lds(
        (const __attribute__((address_space(1))) void*)g,
        (__attribute__((address_space(3))) void*)l, 16, 0, 0);
}

#define WAITV(N) asm volatile("s_waitcnt vmcnt(" #N ")" ::: "memory")
#define SBAR()   asm volatile("s_barrier" ::: "memory")

// ===========================================================================
// gemm128d (round-8 "v2" engine — best measured: W13 117 µs):
// 128x256 tile, BK=64, deep pipeline, 3 LDS buffers (144 KiB), 2-tile
// lookahead, 32-MFMA cluster, ds_read of t+1 after the barrier.
// Swizzle: phys_byte = logical ^ ((row&7)<<4), both-sides. Bank-conflict 0.
// 8 waves 2Mx4N, wave 64x64, acc[4][4]. Weights pre-converted to bf16 BT.
// EPI 1: split-K=2 fp32 partials.  EPI 2: fused SwiGLU -> [M][N/2] bf16.
// EPI 3: split-K=2 + unsafeAtomicAdd into fp32 outP (holds residual h).
// EPI 4: QKV epilogue — RoPE on q/k cols (<4096), V transposed to vT.
// ===========================================================================
#define STAGE128D(KT, BUF)                                                    \
    _Pragma("unroll")                                                         \
    for (int sl = 0; sl < 3; ++sl) {                                          \
        const unsigned short* sbase = (sl == 0)                               \
            ? A  + (size_t)bm * K                                             \
            : BT + (size_t)(bn + (sl - 1) * 128) * K;                         \
        _Pragma("unroll")                                                     \
        for (int j = 0; j < 2; ++j) {                                         \
            const unsigned short* g = sbase + (size_t)(srow + j * 64) * K     \
                                      + koff + (KT) * 64 + lc;                \
            gl2lds16(g, &lds[BUF][sl][wave * 512 + j * 4096]);                \
        }                                                                     \
    }

#define DSREAD128(BUF)                                                        \
    {                                                                         \
        const char* Ab = (const char*)&lds[BUF][0][0];                        \
        const char* Bb = (const char*)&lds[BUF][1 + (wn >> 1)][0];            \
        _Pragma("unroll")                                                     \
        for (int m4 = 0; m4 < 4; ++m4)                                        \
            _Pragma("unroll")                                                 \
            for (int kk = 0; kk < 2; ++kk)                                    \
                a_[m4][kk] = *(const bf16x8*)(Ab +                            \
                    (wm * 64 + m4 * 16 + lr) * 128 +                          \
                    ((kk * 64 + lg * 16) ^ xsw));                             \
        _Pragma("unroll")                                                     \
        for (int n2 = 0; n2 < 4; ++n2)                                        \
            _Pragma("unroll")                                                 \
            for (int kk = 0; kk < 2; ++kk)                                    \
                b_[n2][kk] = *(const bf16x8*)(Bb +                            \
                    ((wn & 1) * 64 + n2 * 16 + lr) * 128 +                    \
                    ((kk * 64 + lg * 16) ^ xsw));                             \
    }

#define MFMA128                                                               \
    __builtin_amdgcn_s_setprio(1);                                            \
    _Pragma("unroll")                                                         \
    for (int m4 = 0; m4 < 4; ++m4)                                            \
        _Pragma("unroll")                                                     \
        for (int n2 = 0; n2 < 4; ++n2)                                        \
            _Pragma("unroll")                                                 \
            for (int kk = 0; kk < 2; ++kk)                                    \
                acc[m4][n2] = __builtin_amdgcn_mfma_f32_16x16x32_bf16(        \
                    a_[m4][kk], b_[n2][kk], acc[m4][n2], 0, 0, 0);            \
    __builtin_amdgcn_s_setprio(0);

template <int EPI>
__global__ __launch_bounds__(512, 2)
void gemm128d(const unsigned short* __restrict__ A,
              const unsigned short* __restrict__ BT,
              unsigned short* __restrict__ outB,
              float* __restrict__ outP,
              int M, int N, int K,
              const float* __restrict__ cs, const float* __restrict__ sn,
              unsigned short* __restrict__ vT)
{
    __shared__ alignas(16) unsigned short lds[3][3][8192];   // 144 KiB
    const int tid  = threadIdx.x;
    const int lane = tid & 63;
    const int wave = tid >> 6;
    const int wm = wave >> 2;
    const int wn = wave & 3;
    const int lr = lane & 15;
    const int lg = lane >> 4;
    const int gy  = gridDim.y;
    const int lin = blockIdx.y * gridDim.x + blockIdx.x;
    const int cpx = (gridDim.x * gy) >> 3;   // grid (x*y) % 8 == 0 required
    const int swz = (lin & 7) * cpx + (lin >> 3);
    const int bm = (swz % gy) * 128;
    const int bn = (swz / gy) * 256;
    const int xsw  = (lr & 7) << 4;
    const int srow = tid >> 3;
    const int lc   = ((tid & 7) ^ (srow & 7)) * 8;
    int koff, NT;
    if constexpr (EPI == 1 || EPI == 3) {
        const int Kh = K >> 1; koff = blockIdx.z * Kh; NT = Kh >> 6;
    } else {
        koff = 0; NT = K >> 6;
    }

    f32x4 acc[4][4] = {};
    bf16x8 a_[4][2], b_[4][2];

    // prologue: stage T0,T1; wait T0; read T0 fragments
    STAGE128D(0, 0);
    STAGE128D(1, 1);
    WAITV(6); SBAR();
    DSREAD128(0);

    int bc = 0;
    for (int kt = 0; kt < NT - 2; ++kt) {
        const int nb = (bc == 0) ? 2 : bc - 1;     // (bc+2)%3
        STAGE128D(kt + 2, nb);
        MFMA128;                                   // tile kt (frags in regs)
        WAITV(6); SBAR();                          // T(kt+1) landed everywhere
        const int rb = (bc == 2) ? 0 : bc + 1;     // (bc+1)%3
        DSREAD128(rb);                             // frags tile kt+1
        bc = rb;
    }
    // kt = NT-2
    MFMA128;
    WAITV(0); SBAR();                              // T(NT-1) landed
    {
        const int rb = (bc == 2) ? 0 : bc + 1;
        DSREAD128(rb);
    }
    // kt = NT-1
    MFMA128;

#pragma unroll
    for (int m4 = 0; m4 < 4; ++m4) {
        const int row = bm + wm * 64 + m4 * 16 + lg * 4;
#pragma unroll
        for (int n2 = 0; n2 < 4; ++n2) {
            const int col = bn + wn * 64 + n2 * 16 + lr;
            if constexpr (EPI == 4) {
                if (bn >= 4096) {
                    // V: write transposed vT[d][s] (8B store, rows contiguous)
                    u16x4 o;
#pragma unroll
                    for (int r = 0; r < 4; ++r) o[r] = f2bf(acc[m4][n2][r]);
                    *(u16x4*)(vT + (size_t)(col - 4096) * 2048 + row) = o;
                } else {
                    // Q/K: RoPE via lane-pair shuffle
#pragma unroll
                    for (int r = 0; r < 4; ++r) {
                        const float v  = acc[m4][n2][r];
                        const float vo = __shfl_xor(v, 1);
                        const int rr = row + r;
                        const int i0 = (col & 127) >> 1;
                        const float c = cs[rr * 64 + i0];
                        const float s = sn[rr * 64 + i0];
                        const float o = (lr & 1) ? (vo * s + v * c)   // im' = re*s+im*c
                                                 : (v * c - vo * s);  // re' = re*c-im*s
                        outB[(size_t)rr * N + col] = f2bf(o);
                    }
                }
            } else {
#pragma unroll
                for (int r = 0; r < 4; ++r) {
                    if constexpr (EPI == 1) {
                        outP[(size_t)blockIdx.z * M * N + (size_t)(row + r) * N + col] = acc[m4][n2][r];
                    } else if constexpr (EPI == 3) {
                        unsafeAtomicAdd(&outP[(size_t)(row + r) * N + col], acc[m4][n2][r]);
                    } else {   // EPI == 2: fused SwiGLU
                        const float v  = acc[m4][n2][r];
                        const float vo = __shfl_xor(v, 1);
                        const float x1 = (lr & 1) ? vo : v;
                        const float x3 = (lr & 1) ? v : vo;
                        const float g  = x1 / (1.0f + __expf(-x1)) * x3;
                        if (!(lr & 1))
                            outB[(size_t)(row + r) * (N >> 1) + (col >> 1)] = f2bf(g);
                    }
                }
            }
        }
    }
}

// h = res + p[0] + p[1]; hout = h; nout = rmsnorm(h)*w  — one block per row.
__global__ __launch_bounds__(256)
void reduce2_norm(const float* __restrict__ res, const float* __restrict__ p,
                  const float* __restrict__ w, float* __restrict__ hout,
                  unsigned short* __restrict__ nout)
{
    const int row = blockIdx.x, tid = threadIdx.x;
    const float4* r4 = (const float4*)(res + (size_t)row * 2048);
    const float4* a4 = (const float4*)(p   + (size_t)row * 2048);
    const float4* b4 = (const float4*)(p + (size_t)2048 * 2048 + (size_t)row * 2048);
    float4* h4 = (float4*)(hout + (size_t)row * 2048);
    float4 h[2];
    float ss = 0.f;
#pragma unroll
    for (int i = 0; i < 2; ++i) {
        const int idx = i * 256 + tid;
        const float4 r = r4[idx], a = a4[idx], b = b4[idx];
        float4 v = make_float4(r.x + a.x + b.x, r.y + a.y + b.y,
                               r.z + a.z + b.z, r.w + a.w + b.w);
        h[i] = v; h4[idx] = v;
        ss += v.x * v.x + v.y * v.y + v.z * v.z + v.w * v.w;
    }
#pragma unroll
    for (int off = 32; off; off >>= 1) ss += __shfl_xor(ss, off);
    __shared__ float red[4];
    if ((tid & 63) == 0) red[tid >> 6] = ss;
    __syncthreads();
    const float tot = red[0] + red[1] + red[2] + red[3];
    const float sc = rsqrtf(tot * (1.0f / 2048.0f) + 1e-5f);
#pragma unroll
    for (int i = 0; i < 2; ++i) {
        const int idx = i * 256 + tid;
        const float4 wv = ((const float4*)w)[idx];
        u16x4 o;
        o[0] = f2bf(h[i].x * sc * wv.x); o[1] = f2bf(h[i].y * sc * wv.y);
        o[2] = f2bf(h[i].z * sc * wv.z); o[3] = f2bf(h[i].w * sc * wv.w);
        *(u16x4*)(nout + (size_t)row * 2048 + idx * 4) = o;
    }
}

// ---------------------------------------------------------------------------
// RMSNorm: fp32 in [2048][2048] -> bf16 out, weight fp32. One block per row.
// ---------------------------------------------------------------------------
__global__ __launch_bounds__(256)
void rmsnorm_kernel(const float* __restrict__ x, const float* __restrict__ w,
                    unsigned short* __restrict__ out)
{
    const int row = blockIdx.x;
    const int tid = threadIdx.x;
    const float* xr = x + (size_t)row * 2048;
    const float4 a = *reinterpret_cast<const float4*>(xr + tid * 8);
    const float4 b = *reinterpret_cast<const float4*>(xr + tid * 8 + 4);
    float ss = a.x * a.x + a.y * a.y + a.z * a.z + a.w * a.w
             + b.x * b.x + b.y * b.y + b.z * b.z + b.w * b.w;
#pragma unroll
    for (int off = 32; off; off >>= 1) ss += __shfl_xor(ss, off);
    __shared__ float red[4];
    if ((tid & 63) == 0) red[tid >> 6] = ss;
    __syncthreads();
    const float tot = red[0] + red[1] + red[2] + red[3];
    const float sc = rsqrtf(tot * (1.0f / 2048.0f) + 1e-5f);
    const float4 wa = *reinterpret_cast<const float4*>(w + tid * 8);
    const float4 wb = *reinterpret_cast<const float4*>(w + tid * 8 + 4);
    u16x8 o;
    o[0] = f2bf(a.x * sc * wa.x); o[1] = f2bf(a.y * sc * wa.y);
    o[2] = f2bf(a.z * sc * wa.z); o[3] = f2bf(a.w * sc * wa.w);
    o[4] = f2bf(b.x * sc * wb.x); o[5] = f2bf(b.y * sc * wb.y);
    o[6] = f2bf(b.z * sc * wb.z); o[7] = f2bf(b.w * sc * wb.w);
    *reinterpret_cast<u16x8*>(out + (size_t)row * 2048 + tid * 8) = o;
}

// ---------------------------------------------------------------------------
// Weight convert + transpose (fp32 [K][N] -> bf16 wT[rmul*n+radd][K]).
// ---------------------------------------------------------------------------
DEV void convT_half(const float* __restrict__ w, unsigned short* __restrict__ wT,
                    int K, int N, int rmul, int radd, int bk, int bn,
                    int tid, unsigned short (*t)[66])
{
    const int r = tid >> 4, c4 = (tid & 15) * 4;
#pragma unroll
    for (int i = 0; i < 4; ++i) {
        const int row = r + i * 16;
        const float4 v = *reinterpret_cast<const float4*>(w + (size_t)(bk + row) * N + bn + c4);
        t[row][c4 + 0] = f2bf(v.x); t[row][c4 + 1] = f2bf(v.y);
        t[row][c4 + 2] = f2bf(v.z); t[row][c4 + 3] = f2bf(v.w);
    }
    __syncthreads();
#pragma unroll
    for (int i = 0; i < 4; ++i) {
        const int n = r + i * 16;
        u16x4 o;
#pragma unroll
        for (int e = 0; e < 4; ++e) o[e] = t[c4 + e][n];
        *reinterpret_cast<u16x4*>(wT + (size_t)(rmul * (bn + n) + radd) * K + bk + c4) = o;
    }
}

// wq/wk/wv (needed before QKV) — standalone dispatch
__global__ __launch_bounds__(256)
void convT3_kernel(const float* __restrict__ w0, const float* __restrict__ w1,
                   const float* __restrict__ w2v, unsigned short* __restrict__ wT)
{
    __shared__ unsigned short t[64][66];
    const int z = blockIdx.z;
    const float* w = (z == 0) ? w0 : (z == 1) ? w1 : w2v;
    convT_half(w, wT + (size_t)z * 2048 * 2048, 2048, 2048, 1, 0,
               blockIdx.y * 64, blockIdx.x * 64, threadIdx.x, t);
}

// tile decode for mega convT: t2 in [0, 9472)
DEV void ct_decode(int t2,
                   const float* wo, const float* w1, const float* w3,
                   const float* w2,
                   unsigned short* woT, unsigned short* w13T, unsigned short* w2T,
                   const float*& w, unsigned short*& wT,
                   int& K, int& N, int& rmul, int& radd, int& bk, int& bn)
{
    if (t2 < 1024) {
        w = wo; wT = woT; K = 2048; N = 2048; rmul = 1; radd = 0;
        bk = (t2 >> 5) * 64; bn = (t2 & 31) * 64;
    } else if (t2 < 6656) {
        const int u = t2 - 1024;
        const int z = u / 2816, rm = u % 2816;
        w = z ? w3 : w1; wT = w13T; K = 2048; N = 5632; rmul = 2; radd = z;
        bk = (rm / 88) * 64; bn = (rm % 88) * 64;
    } else {
        const int u = t2 - 6656;
        w = w2; wT = w2T; K = 5632; N = 2048; rmul = 1; radd = 0;
        bk = (u / 32) * 64; bn = (u % 32) * 64;
    }
}

// ---------------------------------------------------------------------------
// MEGA kernel v3: blocks 0..255 = flash attention; 256..767 = convT workers.
// Flash LDS cut to 71.7 KiB (single-buffer V, K stays double-buffered) ->
// 2 blocks/CU: convT blocks become CO-RESIDENT with flash (BW-bound convT
// overlaps latency-bound flash) and flash barriers are covered.
// Flash stage: gload(kt+1) -> compute(QK^T, softmax, PV on V(kt)) ->
//   KwriteLDS(kt+1 -> buf^1) -> barrier -> VwriteLDS(kt+1) -> barrier.
// Hazards: V(kt) reads precede barrier-1 -> Vwrite(kt+1) safe; V(kt+1)
// published by barrier-2 before PV(kt+1); Ks[buf^1] last read 2 barriers ago.
// ---------------------------------------------------------------------------
__global__ __launch_bounds__(512, 4)
void flash_mega(const unsigned short* __restrict__ q,
                const unsigned short* __restrict__ k,
                const unsigned short* __restrict__ vT,
                unsigned short* __restrict__ attn,
                const float* __restrict__ wo, const float* __restrict__ w1,
                const float* __restrict__ w3, const float* __restrict__ w2,
                unsigned short* __restrict__ woT,
                unsigned short* __restrict__ w13T,
                unsigned short* __restrict__ w2T)
{
    __shared__ alignas(16) unsigned short Ks[2][64][136];  // [buf][kv][hd] 34.8K
    __shared__ alignas(16) unsigned short Vs[128][72];     // [hd][kv] single 18.4K
    __shared__ alignas(16) unsigned short Ps[8][16][72];   // per-wave P  18.4K

    const int bid = blockIdx.x;
    const int tid = threadIdx.x;

    if (bid >= 256) {   // ---- convT grid-stride role ----
        const int half = tid >> 8;
        const int t256 = tid & 255;
        const int gid  = (bid - 256) * 2 + half;            // 0..1023
        const int r = t256 >> 4, c4 = (t256 & 15) * 4;
        // transpose buffer aliases Ks storage (2 x 64x66 u16 = 16.9 KB < 34.8)
        unsigned short (*tb)[66] =
            (unsigned short (*)[66])(&Ks[0][0][0] + half * 64 * 66);
        const int TOT = 9472;

        float4 cur[4], nxt[4];
        const float* wC; unsigned short* wTC;
        int KC, NC, rmC, raC, bkC, bnC;
        int t2 = gid;
        bool act = (t2 < TOT);
        if (act) {
            ct_decode(t2, wo, w1, w3, w2, woT, w13T, w2T,
                      wC, wTC, KC, NC, rmC, raC, bkC, bnC);
#pragma unroll
            for (int i = 0; i < 4; ++i)
                cur[i] = *(const float4*)(wC + (size_t)(bkC + r + i * 16) * NC + bnC + c4);
        }
#pragma unroll 1
        for (int it = 0; it < 10; ++it) {
            const int t2n = t2 + 1024;
            const bool actn = (t2n < TOT);
            const float* wN; unsigned short* wTN;
            int KN, NN, rmN, raN, bkN, bnN;
            if (actn) {   // issue next tile's loads early
                ct_decode(t2n, wo, w1, w3, w2, woT, w13T, w2T,
                          wN, wTN, KN, NN, rmN, raN, bkN, bnN);
#pragma unroll
                for (int i = 0; i < 4; ++i)
                    nxt[i] = *(const float4*)(wN + (size_t)(bkN + r + i * 16) * NN + bnN + c4);
            }
            if (act) {    // transpose current tile through LDS
#pragma unroll
                for (int i = 0; i < 4; ++i) {
                    const int row = r + i * 16;
                    tb[row][c4 + 0] = f2bf(cur[i].x);
                    tb[row][c4 + 1] = f2bf(cur[i].y);
                    tb[row][c4 + 2] = f2bf(cur[i].z);
                    tb[row][c4 + 3] = f2bf(cur[i].w);
                }
            }
            __syncthreads();
            if (act) {
#pragma unroll
                for (int i = 0; i < 4; ++i) {
                    const int n = r + i * 16;
                    u16x4 o;
#pragma unroll
                    for (int e = 0; e < 4; ++e) o[e] = tb[c4 + e][n];
                    *reinterpret_cast<u16x4*>(
                        wTC + (size_t)(rmC * (bnC + n) + raC) * KC + bkC + c4) = o;
                }
            }
            __syncthreads();
            // rotate
            t2 = t2n; act = actn;
            if (actn) {
                wC = wN; wTC = wTN; KC = KN; NC = NN;
                rmC = rmN; raC = raN; bkC = bkN; bnC = bnN;
#pragma unroll
                for (int i = 0; i < 4; ++i) cur[i] = nxt[i];
            }
        }
        return;
    }

    // ---- flash attention role ----
    const int hh = bid >> 4;
    const int pi = bid & 15;                // 0..15
    const int lane = tid & 63, wave = tid >> 6;
    const int qt = (wave >> 2) ? (31 - pi) : pi;
    const int lr = lane & 15, lg = lane >> 4;
    const int q0 = qt * 64 + (wave & 3) * 16;
    const int myNT = qt + 1;
    const int NT   = 32 - pi;

    const int kr0 = tid >> 4, kc0 = (tid & 15) * 8;
    const int vr0 = tid >> 3, vc0 = (tid & 7) * 8;

    bf16x8 qf[4];
#pragma unroll
    for (int c = 0; c < 4; ++c)
        qf[c] = *reinterpret_cast<const bf16x8*>(
            q + (size_t)(q0 + lr) * 6144 + hh * 128 + c * 32 + lg * 8);

    f32x4 oacc[8] = {};
    float m_r[4], l_r[4];
#pragma unroll
    for (int r = 0; r < 4; ++r) { m_r[r] = -INFINITY; l_r[r] = 0.0f; }
    const float scale = 0.08838834764831845f;   // 1/sqrt(128)

    u16x8 kreg0, kreg1, vreg0, vreg1;
    auto gload = [&](int kt) {
        const int kv0 = kt * 64;
        kreg0 = *reinterpret_cast<const u16x8*>(k + (size_t)(kv0 + kr0) * 6144 + hh * 128 + kc0);
        kreg1 = *reinterpret_cast<const u16x8*>(k + (size_t)(kv0 + kr0 + 32) * 6144 + hh * 128 + kc0);
        vreg0 = *reinterpret_cast<const u16x8*>(vT + (size_t)(hh * 128 + vr0) * 2048 + kv0 + vc0);
        vreg1 = *reinterpret_cast<const u16x8*>(vT + (size_t)(hh * 128 + vr0 + 64) * 2048 + kv0 + vc0);
    };
    auto lwriteK = [&](int buf) {
        *reinterpret_cast<u16x8*>(&Ks[buf][kr0][kc0])      = kreg0;
        *reinterpret_cast<u16x8*>(&Ks[buf][kr0 + 32][kc0]) = kreg1;
    };
    auto lwriteV = [&]() {
        *reinterpret_cast<u16x8*>(&Vs[vr0][vc0])      = vreg0;
        *reinterpret_cast<u16x8*>(&Vs[vr0 + 64][vc0]) = vreg1;
    };

    gload(0);
    lwriteK(0);
    lwriteV();
    __syncthreads();

    for (int kt = 0; kt < NT; ++kt) {
        const int buf = kt & 1;
        if (kt + 1 < NT) gload(kt + 1);

        if (kt < myNT) {
            const int kv0 = kt * 64;
            const bool masked = (kt == myNT - 1);
            f32x4 s[4] = {};
            __builtin_amdgcn_s_setprio(1);
#pragma unroll
            for (int ct = 0; ct < 4; ++ct)
#pragma unroll
                for (int c = 0; c < 4; ++c) {
                    const bf16x8 kf = *reinterpret_cast<const bf16x8*>(
                        &Ks[buf][ct * 16 + lr][c * 32 + lg * 8]);
                    s[ct] = __builtin_amdgcn_mfma_f32_16x16x32_bf16(qf[c], kf, s[ct], 0, 0, 0);
                }
            __builtin_amdgcn_s_setprio(0);
#pragma unroll
            for (int ct = 0; ct < 4; ++ct)
#pragma unroll
                for (int r = 0; r < 4; ++r) {
                    float v = s[ct][r] * scale;
                    if (masked) {
                        const int kvg = kv0 + ct * 16 + lr;
                        const int qg  = q0 + lg * 4 + r;
                        if (kvg > qg) v = -INFINITY;
                    }
                    s[ct][r] = v;
                }
            float mn[4], alpha[4], rs[4];
#pragma unroll
            for (int r = 0; r < 4; ++r) {
                float v = fmaxf(fmaxf(s[0][r], s[1][r]), fmaxf(s[2][r], s[3][r]));
                v = fmaxf(v, __shfl_xor(v, 1));
                v = fmaxf(v, __shfl_xor(v, 2));
                v = fmaxf(v, __shfl_xor(v, 4));
                v = fmaxf(v, __shfl_xor(v, 8));
                mn[r] = fmaxf(m_r[r], v);
                alpha[r] = __expf(m_r[r] - mn[r]);
                m_r[r] = mn[r];
                rs[r] = 0.0f;
            }
#pragma unroll
            for (int ct = 0; ct < 4; ++ct)
#pragma unroll
                for (int r = 0; r < 4; ++r) {
                    const float p = __expf(s[ct][r] - mn[r]);
                    s[ct][r] = p;
                    rs[r] += p;
                }
#pragma unroll
            for (int r = 0; r < 4; ++r) {
                float t2 = rs[r];
                t2 += __shfl_xor(t2, 1);
                t2 += __shfl_xor(t2, 2);
                t2 += __shfl_xor(t2, 4);
                t2 += __shfl_xor(t2, 8);
                l_r[r] = l_r[r] * alpha[r] + t2;
            }
#pragma unroll
            for (int ot = 0; ot < 8; ++ot)
#pragma unroll
                for (int r = 0; r < 4; ++r) oacc[ot][r] *= alpha[r];

#pragma unroll
            for (int ct = 0; ct < 4; ++ct)
#pragma unroll
                for (int r = 0; r < 4; ++r)
                    Ps[wave][lg * 4 + r][ct * 16 + lr] = f2bf(s[ct][r]);

            __builtin_amdgcn_s_setprio(1);
#pragma unroll
            for (int c2 = 0; c2 < 2; ++c2) {
                const bf16x8 pf = *reinterpret_cast<const bf16x8*>(
                    &Ps[wave][lr][c2 * 32 + lg * 8]);
#pragma unroll
                for (int ot = 0; ot < 8; ++ot) {
                    const bf16x8 vf = *reinterpret_cast<const bf16x8*>(
                        &Vs[ot * 16 + lr][c2 * 32 + lg * 8]);
                    oacc[ot] = __builtin_amdgcn_mfma_f32_16x16x32_bf16(pf, vf, oacc[ot], 0, 0, 0);
                }
            }
            __builtin_amdgcn_s_setprio(0);
        }

        if (kt + 1 < NT) lwriteK(buf ^ 1);
        __syncthreads();                 // PV(kt) reads done; K(kt+1) published
        if (kt + 1 < NT) lwriteV();
        __syncthreads();                 // V(kt+1) published
    }

#pragma unroll
    for (int ot = 0; ot < 8; ++ot)
#pragma unroll
        for (int r = 0; r < 4; ++r) {
            const float v = oacc[ot][r] / l_r[r];
            attn[(size_t)(q0 + lg * 4 + r) * 2048 + hh * 128 + ot * 16 + lr] = f2bf(v);
        }
}

// ---------------------------------------------------------------------------
extern "C" void kernel_launch(void* const* d_in, const int* in_sizes, int n_in,
                              void* d_out, int out_size, void* d_ws, size_t ws_size,
                              hipStream_t stream)
{
    const float* x    = (const float*)d_in[0];
    const float* fcos = (const float*)d_in[1];
    const float* fsin = (const float*)d_in[2];
    // d_in[3] = mask (causal, hardcoded)
    const float* wq  = (const float*)d_in[4];
    const float* wk  = (const float*)d_in[5];
    const float* wv  = (const float*)d_in[6];
    const float* wo  = (const float*)d_in[7];
    const float* w1  = (const float*)d_in[8];
    const float* w2  = (const float*)d_in[9];
    const float* w3  = (const float*)d_in[10];
    const float* anw = (const float*)d_in[11];
    const float* fnw = (const float*)d_in[12];
    float* out = (float*)d_out;

    char* ws = (char*)d_ws;
    size_t off = 0;
    auto alloc = [&](size_t bytes) { void* p = ws + off; off += bytes; return p; };
    const size_t SZ_DD = (size_t)2048 * 2048 * 2;   // 8 MiB
    const size_t SZ_DF = (size_t)2048 * 5632 * 2;   // 22 MiB

    unsigned short* qkvoT = (unsigned short*)alloc(4 * SZ_DD);  // wq|wk|wv|wo T
    unsigned short* w13T  = (unsigned short*)alloc(2 * SZ_DF);  // interleaved [11264][2048]
    unsigned short* w2T   = (unsigned short*)alloc(SZ_DF);

    // region1 (48 MiB), attn phase: xn[0:8) | qkv[8:32) | vTb[32:40) | ab[40:48)
    // pk (32 MiB fp32 split-K partials for Wo) overlays [0:32) when dead;
    // hn overlays vTb's region [32:40) (vTb dead after flash).
    char* reg1 = (char*)alloc((size_t)48 * 1024 * 1024);
    unsigned short* xn   = (unsigned short*)reg1;
    unsigned short* qkv  = (unsigned short*)(reg1 + SZ_DD);            // [2048][6144]
    unsigned short* vTb  = (unsigned short*)(reg1 + SZ_DD + 3 * SZ_DD);
    unsigned short* ab   = (unsigned short*)(reg1 + SZ_DD + 4 * SZ_DD);
    float*          pk   = (float*)reg1;                               // [2][2048][2048] f32
    unsigned short* hn   = (unsigned short*)(reg1 + 4 * SZ_DD);        // [2048][2048]

    char* reg2 = (char*)alloc(SZ_DF);
    unsigned short* t1 = (unsigned short*)reg2;                        // [2048][5632]

    // wq/wk/wv fp32 -> bf16 transposed (needed by QKV)
    convT3_kernel<<<dim3(32, 32, 3), 256, 0, stream>>>(wq, wk, wv, qkvoT);

    // attention block
    rmsnorm_kernel<<<2048, 256, 0, stream>>>(x, anw, xn);
    // fused QKV + RoPE + V-transpose (384 blocks)
    gemm128d<4><<<dim3(24, 16), 512, 0, stream>>>(xn, qkvoT, qkv, nullptr,
                                                  2048, 6144, 2048, fcos, fsin, vTb);
    // flash attention + co-resident convT for wo / {w1,w3} / w2
    flash_mega<<<768, 512, 0, stream>>>(qkv, qkv + 2048, vTb, ab,
                                        wo, w1, w3, w2,
                                        qkvoT + 3 * (size_t)2048 * 2048, w13T, w2T);
    // Wo split-K=2
    gemm128d<1><<<dim3(8, 16, 2), 512, 0, stream>>>(ab, qkvoT + 3 * (size_t)2048 * 2048,
                                                    nullptr, pk, 2048, 2048, 2048,
                                                    nullptr, nullptr, nullptr);
    // fused: out = x + Wo-partials; hn = rmsnorm(out) * fnw
    reduce2_norm<<<2048, 256, 0, stream>>>(x, pk, fnw, out, hn);

    // FFN block
    // W13 + fused SwiGLU epilogue: t1 = silu(hn@w1) * (hn@w3), 704 blocks
    gemm128d<2><<<dim3(44, 16), 512, 0, stream>>>(hn, w13T, t1, nullptr,
                                                  2048, 11264, 2048,
                                                  nullptr, nullptr, nullptr);
    // W2 split-K=2 with atomic residual add into out (out already holds h)
    gemm128d<3><<<dim3(8, 16, 2), 512, 0, stream>>>(t1, w2T, nullptr, out,
                                                    2048, 2048, 5632,
                                                    nullptr, nullptr, nullptr);
}

// Round 16
// 400.730 us; speedup vs baseline: 1.0582x; 1.0033x over previous
//
#include <hip/hip_runtime.h>
#include <hip/hip_bf16.h>

typedef __bf16 bf16x8 __attribute__((ext_vector_type(8)));
typedef float f32x4 __attribute__((ext_vector_type(4)));
typedef unsigned short u16x8 __attribute__((ext_vector_type(8)));
typedef unsigned short u16x4 __attribute__((ext_vector_type(4)));

#define DEV static __device__ __forceinline__

DEV unsigned short f2bf(float f) {
    unsigned u = __builtin_bit_cast(unsigned, f);
    u += 0x7fffu + ((u >> 16) & 1u);   // round-to-nearest-even
    return (unsigned short)(u >> 16);
}
DEV float bf2f(unsigned short h) {
    unsigned u = ((unsigned)h) << 16;
    return __builtin_bit_cast(float, u);
}

DEV void gl2lds16(const void* g, void* l) {
    __builtin_amdgcn_global_load_lds(
        (const __attribute__((address_space(1))) void*)g,
        (__attribute__((address_space(3))) void*)l, 16, 0, 0);
}

#define WAITV(N) asm volatile("s_waitcnt vmcnt(" #N ")" ::: "memory")
#define SBAR()   asm volatile("s_barrier" ::: "memory")

// ===========================================================================
// gemm128d (round-8 "v2" engine): 128x256 tile, BK=64, deep pipeline,
// 3 LDS buffers (144 KiB), 2-tile lookahead, 32-MFMA cluster.
// Swizzle: phys_byte = logical ^ ((row&7)<<4), both-sides. Bank-conflict 0.
// EPI 1: split-K=2 fp32 partials.  EPI 2: fused SwiGLU -> [M][N/2] bf16.
// EPI 3: split-K=2 + unsafeAtomicAdd into fp32 outP (holds residual h).
// EPI 4: QKV epilogue — RoPE on q/k cols (<4096), V transposed to vT.
// ===========================================================================
#define STAGE128D(KT, BUF)                                                    \
    _Pragma("unroll")                                                         \
    for (int sl = 0; sl < 3; ++sl) {                                          \
        const unsigned short* sbase = (sl == 0)                               \
            ? A  + (size_t)bm * K                                             \
            : BT + (size_t)(bn + (sl - 1) * 128) * K;                         \
        _Pragma("unroll")                                                     \
        for (int j = 0; j < 2; ++j) {                                         \
            const unsigned short* g = sbase + (size_t)(srow + j * 64) * K     \
                                      + koff + (KT) * 64 + lc;                \
            gl2lds16(g, &lds[BUF][sl][wave * 512 + j * 4096]);                \
        }                                                                     \
    }

#define DSREAD128(BUF)                                                        \
    {                                                                         \
        const char* Ab = (const char*)&lds[BUF][0][0];                        \
        const char* Bb = (const char*)&lds[BUF][1 + (wn >> 1)][0];            \
        _Pragma("unroll")                                                     \
        for (int m4 = 0; m4 < 4; ++m4)                                        \
            _Pragma("unroll")                                                 \
            for (int kk = 0; kk < 2; ++kk)                                    \
                a_[m4][kk] = *(const bf16x8*)(Ab +                            \
                    (wm * 64 + m4 * 16 + lr) * 128 +                          \
                    ((kk * 64 + lg * 16) ^ xsw));                             \
        _Pragma("unroll")                                                     \
        for (int n2 = 0; n2 < 4; ++n2)                                        \
            _Pragma("unroll")                                                 \
            for (int kk = 0; kk < 2; ++kk)                                    \
                b_[n2][kk] = *(const bf16x8*)(Bb +                            \
                    ((wn & 1) * 64 + n2 * 16 + lr) * 128 +                    \
                    ((kk * 64 + lg * 16) ^ xsw));                             \
    }

#define MFMA128                                                               \
    __builtin_amdgcn_s_setprio(1);                                            \
    _Pragma("unroll")                                                         \
    for (int m4 = 0; m4 < 4; ++m4)                                            \
        _Pragma("unroll")                                                     \
        for (int n2 = 0; n2 < 4; ++n2)                                        \
            _Pragma("unroll")                                                 \
            for (int kk = 0; kk < 2; ++kk)                                    \
                acc[m4][n2] = __builtin_amdgcn_mfma_f32_16x16x32_bf16(        \
                    a_[m4][kk], b_[n2][kk], acc[m4][n2], 0, 0, 0);            \
    __builtin_amdgcn_s_setprio(0);

template <int EPI>
__global__ __launch_bounds__(512, 2)
void gemm128d(const unsigned short* __restrict__ A,
              const unsigned short* __restrict__ BT,
              unsigned short* __restrict__ outB,
              float* __restrict__ outP,
              int M, int N, int K,
              const float* __restrict__ cs, const float* __restrict__ sn,
              unsigned short* __restrict__ vT)
{
    __shared__ alignas(16) unsigned short lds[3][3][8192];   // 144 KiB
    const int tid  = threadIdx.x;
    const int lane = tid & 63;
    const int wave = tid >> 6;
    const int wm = wave >> 2;
    const int wn = wave & 3;
    const int lr = lane & 15;
    const int lg = lane >> 4;
    const int gy  = gridDim.y;
    const int lin = blockIdx.y * gridDim.x + blockIdx.x;
    const int cpx = (gridDim.x * gy) >> 3;   // grid (x*y) % 8 == 0 required
    const int swz = (lin & 7) * cpx + (lin >> 3);
    const int bm = (swz % gy) * 128;
    const int bn = (swz / gy) * 256;
    const int xsw  = (lr & 7) << 4;
    const int srow = tid >> 3;
    const int lc   = ((tid & 7) ^ (srow & 7)) * 8;
    int koff, NT;
    if constexpr (EPI == 1 || EPI == 3) {
        const int Kh = K >> 1; koff = blockIdx.z * Kh; NT = Kh >> 6;
    } else {
        koff = 0; NT = K >> 6;
    }

    f32x4 acc[4][4] = {};
    bf16x8 a_[4][2], b_[4][2];

    STAGE128D(0, 0);
    STAGE128D(1, 1);
    WAITV(6); SBAR();
    DSREAD128(0);

    int bc = 0;
    for (int kt = 0; kt < NT - 2; ++kt) {
        const int nb = (bc == 0) ? 2 : bc - 1;     // (bc+2)%3
        STAGE128D(kt + 2, nb);
        MFMA128;                                   // tile kt (frags in regs)
        WAITV(6); SBAR();                          // T(kt+1) landed everywhere
        const int rb = (bc == 2) ? 0 : bc + 1;     // (bc+1)%3
        DSREAD128(rb);                             // frags tile kt+1
        bc = rb;
    }
    MFMA128;
    WAITV(0); SBAR();
    {
        const int rb = (bc == 2) ? 0 : bc + 1;
        DSREAD128(rb);
    }
    MFMA128;

#pragma unroll
    for (int m4 = 0; m4 < 4; ++m4) {
        const int row = bm + wm * 64 + m4 * 16 + lg * 4;
#pragma unroll
        for (int n2 = 0; n2 < 4; ++n2) {
            const int col = bn + wn * 64 + n2 * 16 + lr;
            if constexpr (EPI == 4) {
                if (bn >= 4096) {
                    u16x4 o;
#pragma unroll
                    for (int r = 0; r < 4; ++r) o[r] = f2bf(acc[m4][n2][r]);
                    *(u16x4*)(vT + (size_t)(col - 4096) * 2048 + row) = o;
                } else {
#pragma unroll
                    for (int r = 0; r < 4; ++r) {
                        const float v  = acc[m4][n2][r];
                        const float vo = __shfl_xor(v, 1);
                        const int rr = row + r;
                        const int i0 = (col & 127) >> 1;
                        const float c = cs[rr * 64 + i0];
                        const float s = sn[rr * 64 + i0];
                        const float o = (lr & 1) ? (vo * s + v * c)
                                                 : (v * c - vo * s);
                        outB[(size_t)rr * N + col] = f2bf(o);
                    }
                }
            } else {
#pragma unroll
                for (int r = 0; r < 4; ++r) {
                    if constexpr (EPI == 1) {
                        outP[(size_t)blockIdx.z * M * N + (size_t)(row + r) * N + col] = acc[m4][n2][r];
                    } else if constexpr (EPI == 3) {
                        unsafeAtomicAdd(&outP[(size_t)(row + r) * N + col], acc[m4][n2][r]);
                    } else {   // EPI == 2: fused SwiGLU
                        const float v  = acc[m4][n2][r];
                        const float vo = __shfl_xor(v, 1);
                        const float x1 = (lr & 1) ? vo : v;
                        const float x3 = (lr & 1) ? v : vo;
                        const float g  = x1 / (1.0f + __expf(-x1)) * x3;
                        if (!(lr & 1))
                            outB[(size_t)(row + r) * (N >> 1) + (col >> 1)] = f2bf(g);
                    }
                }
            }
        }
    }
}

// h = res + p[0] + p[1]; hout = h; nout = rmsnorm(h)*w  — one block per row.
__global__ __launch_bounds__(256)
void reduce2_norm(const float* __restrict__ res, const float* __restrict__ p,
                  const float* __restrict__ w, float* __restrict__ hout,
                  unsigned short* __restrict__ nout)
{
    const int row = blockIdx.x, tid = threadIdx.x;
    const float4* r4 = (const float4*)(res + (size_t)row * 2048);
    const float4* a4 = (const float4*)(p   + (size_t)row * 2048);
    const float4* b4 = (const float4*)(p + (size_t)2048 * 2048 + (size_t)row * 2048);
    float4* h4 = (float4*)(hout + (size_t)row * 2048);
    float4 h[2];
    float ss = 0.f;
#pragma unroll
    for (int i = 0; i < 2; ++i) {
        const int idx = i * 256 + tid;
        const float4 r = r4[idx], a = a4[idx], b = b4[idx];
        float4 v = make_float4(r.x + a.x + b.x, r.y + a.y + b.y,
                               r.z + a.z + b.z, r.w + a.w + b.w);
        h[i] = v; h4[idx] = v;
        ss += v.x * v.x + v.y * v.y + v.z * v.z + v.w * v.w;
    }
#pragma unroll
    for (int off = 32; off; off >>= 1) ss += __shfl_xor(ss, off);
    __shared__ float red[4];
    if ((tid & 63) == 0) red[tid >> 6] = ss;
    __syncthreads();
    const float tot = red[0] + red[1] + red[2] + red[3];
    const float sc = rsqrtf(tot * (1.0f / 2048.0f) + 1e-5f);
#pragma unroll
    for (int i = 0; i < 2; ++i) {
        const int idx = i * 256 + tid;
        const float4 wv = ((const float4*)w)[idx];
        u16x4 o;
        o[0] = f2bf(h[i].x * sc * wv.x); o[1] = f2bf(h[i].y * sc * wv.y);
        o[2] = f2bf(h[i].z * sc * wv.z); o[3] = f2bf(h[i].w * sc * wv.w);
        *(u16x4*)(nout + (size_t)row * 2048 + idx * 4) = o;
    }
}

// ---------------------------------------------------------------------------
// Weight convert + transpose body (fp32 [K][N] -> bf16 wT[rmul*n+radd][K]).
// ---------------------------------------------------------------------------
DEV void convT_half(const float* __restrict__ w, unsigned short* __restrict__ wT,
                    int K, int N, int rmul, int radd, int bk, int bn,
                    int tid, unsigned short (*t)[66])
{
    const int r = tid >> 4, c4 = (tid & 15) * 4;
#pragma unroll
    for (int i = 0; i < 4; ++i) {
        const int row = r + i * 16;
        const float4 v = *reinterpret_cast<const float4*>(w + (size_t)(bk + row) * N + bn + c4);
        t[row][c4 + 0] = f2bf(v.x); t[row][c4 + 1] = f2bf(v.y);
        t[row][c4 + 2] = f2bf(v.z); t[row][c4 + 3] = f2bf(v.w);
    }
    __syncthreads();
#pragma unroll
    for (int i = 0; i < 4; ++i) {
        const int n = r + i * 16;
        u16x4 o;
#pragma unroll
        for (int e = 0; e < 4; ++e) o[e] = t[c4 + e][n];
        *reinterpret_cast<u16x4*>(wT + (size_t)(rmul * (bn + n) + radd) * K + bk + c4) = o;
    }
}

// ---------------------------------------------------------------------------
// prep: blocks 0..2047 = rmsnorm rows (xn = rmsnorm(x)*anw);
//       blocks 2048..5119 = convT tiles for wq/wk/wv -> qkvoT.
// Both independent pre-QKV work; merged to overlap two BW-bound phases.
// ---------------------------------------------------------------------------
__global__ __launch_bounds__(256)
void prep_kernel(const float* __restrict__ x, const float* __restrict__ anw,
                 unsigned short* __restrict__ xn,
                 const float* __restrict__ wq, const float* __restrict__ wk,
                 const float* __restrict__ wv, unsigned short* __restrict__ qkvoT)
{
    __shared__ unsigned short t[64][66];   // convT transpose buf; rmsnorm red[] aliases
    const int bid = blockIdx.x, tid = threadIdx.x;

    if (bid >= 2048) {   // convT role
        const int u = bid - 2048;          // 0..3071
        const int z = u >> 10;             // 0..2 : wq,wk,wv
        const int idx = u & 1023;
        const float* w = (z == 0) ? wq : (z == 1) ? wk : wv;
        convT_half(w, qkvoT + (size_t)z * 2048 * 2048, 2048, 2048, 1, 0,
                   (idx >> 5) * 64, (idx & 31) * 64, tid, t);
        return;
    }

    // rmsnorm role
    float* red = (float*)&t[0][0];
    const int row = bid;
    const float* xr = x + (size_t)row * 2048;
    const float4 a = *reinterpret_cast<const float4*>(xr + tid * 8);
    const float4 b = *reinterpret_cast<const float4*>(xr + tid * 8 + 4);
    float ss = a.x * a.x + a.y * a.y + a.z * a.z + a.w * a.w
             + b.x * b.x + b.y * b.y + b.z * b.z + b.w * b.w;
#pragma unroll
    for (int off = 32; off; off >>= 1) ss += __shfl_xor(ss, off);
    if ((tid & 63) == 0) red[tid >> 6] = ss;
    __syncthreads();
    const float tot = red[0] + red[1] + red[2] + red[3];
    const float sc = rsqrtf(tot * (1.0f / 2048.0f) + 1e-5f);
    const float4 wa = *reinterpret_cast<const float4*>(anw + tid * 8);
    const float4 wb = *reinterpret_cast<const float4*>(anw + tid * 8 + 4);
    u16x8 o;
    o[0] = f2bf(a.x * sc * wa.x); o[1] = f2bf(a.y * sc * wa.y);
    o[2] = f2bf(a.z * sc * wa.z); o[3] = f2bf(a.w * sc * wa.w);
    o[4] = f2bf(b.x * sc * wb.x); o[5] = f2bf(b.y * sc * wb.y);
    o[6] = f2bf(b.z * sc * wb.z); o[7] = f2bf(b.w * sc * wb.w);
    *reinterpret_cast<u16x8*>(xn + (size_t)row * 2048 + tid * 8) = o;
}

// tile decode for mega convT: t2 in [0, 9472)
DEV void ct_decode(int t2,
                   const float* wo, const float* w1, const float* w3,
                   const float* w2,
                   unsigned short* woT, unsigned short* w13T, unsigned short* w2T,
                   const float*& w, unsigned short*& wT,
                   int& K, int& N, int& rmul, int& radd, int& bk, int& bn)
{
    if (t2 < 1024) {
        w = wo; wT = woT; K = 2048; N = 2048; rmul = 1; radd = 0;
        bk = (t2 >> 5) * 64; bn = (t2 & 31) * 64;
    } else if (t2 < 6656) {
        const int u = t2 - 1024;
        const int z = u / 2816, rm = u % 2816;
        w = z ? w3 : w1; wT = w13T; K = 2048; N = 5632; rmul = 2; radd = z;
        bk = (rm / 88) * 64; bn = (rm % 88) * 64;
    } else {
        const int u = t2 - 6656;
        w = w2; wT = w2T; K = 5632; N = 2048; rmul = 1; radd = 0;
        bk = (u / 32) * 64; bn = (u % 32) * 64;
    }
}

// ---------------------------------------------------------------------------
// MEGA kernel: blocks 0..255 = flash attention (single-buffer V, 71.7 KiB
// LDS -> 2 blocks/CU, convT co-resident); 256..767 = convT grid-stride
// workers for wo / {w1,w3} / w2.  Flash adds T13 defer-max rescale.
// ---------------------------------------------------------------------------
__global__ __launch_bounds__(512, 4)
void flash_mega(const unsigned short* __restrict__ q,
                const unsigned short* __restrict__ k,
                const unsigned short* __restrict__ vT,
                unsigned short* __restrict__ attn,
                const float* __restrict__ wo, const float* __restrict__ w1,
                const float* __restrict__ w3, const float* __restrict__ w2,
                unsigned short* __restrict__ woT,
                unsigned short* __restrict__ w13T,
                unsigned short* __restrict__ w2T)
{
    __shared__ alignas(16) unsigned short Ks[2][64][136];  // [buf][kv][hd] 34.8K
    __shared__ alignas(16) unsigned short Vs[128][72];     // [hd][kv] single 18.4K
    __shared__ alignas(16) unsigned short Ps[8][16][72];   // per-wave P  18.4K

    const int bid = blockIdx.x;
    const int tid = threadIdx.x;

    if (bid >= 256) {   // ---- convT grid-stride role ----
        const int half = tid >> 8;
        const int t256 = tid & 255;
        const int gid  = (bid - 256) * 2 + half;            // 0..1023
        const int r = t256 >> 4, c4 = (t256 & 15) * 4;
        unsigned short (*tb)[66] =
            (unsigned short (*)[66])(&Ks[0][0][0] + half * 64 * 66);
        const int TOT = 9472;

        float4 cur[4], nxt[4];
        const float* wC; unsigned short* wTC;
        int KC, NC, rmC, raC, bkC, bnC;
        int t2 = gid;
        bool act = (t2 < TOT);
        if (act) {
            ct_decode(t2, wo, w1, w3, w2, woT, w13T, w2T,
                      wC, wTC, KC, NC, rmC, raC, bkC, bnC);
#pragma unroll
            for (int i = 0; i < 4; ++i)
                cur[i] = *(const float4*)(wC + (size_t)(bkC + r + i * 16) * NC + bnC + c4);
        }
#pragma unroll 1
        for (int it = 0; it < 10; ++it) {
            const int t2n = t2 + 1024;
            const bool actn = (t2n < TOT);
            const float* wN; unsigned short* wTN;
            int KN, NN, rmN, raN, bkN, bnN;
            if (actn) {
                ct_decode(t2n, wo, w1, w3, w2, woT, w13T, w2T,
                          wN, wTN, KN, NN, rmN, raN, bkN, bnN);
#pragma unroll
                for (int i = 0; i < 4; ++i)
                    nxt[i] = *(const float4*)(wN + (size_t)(bkN + r + i * 16) * NN + bnN + c4);
            }
            if (act) {
#pragma unroll
                for (int i = 0; i < 4; ++i) {
                    const int row = r + i * 16;
                    tb[row][c4 + 0] = f2bf(cur[i].x);
                    tb[row][c4 + 1] = f2bf(cur[i].y);
                    tb[row][c4 + 2] = f2bf(cur[i].z);
                    tb[row][c4 + 3] = f2bf(cur[i].w);
                }
            }
            __syncthreads();
            if (act) {
#pragma unroll
                for (int i = 0; i < 4; ++i) {
                    const int n = r + i * 16;
                    u16x4 o;
#pragma unroll
                    for (int e = 0; e < 4; ++e) o[e] = tb[c4 + e][n];
                    *reinterpret_cast<u16x4*>(
                        wTC + (size_t)(rmC * (bnC + n) + raC) * KC + bkC + c4) = o;
                }
            }
            __syncthreads();
            t2 = t2n; act = actn;
            if (actn) {
                wC = wN; wTC = wTN; KC = KN; NC = NN;
                rmC = rmN; raC = raN; bkC = bkN; bnC = bnN;
#pragma unroll
                for (int i = 0; i < 4; ++i) cur[i] = nxt[i];
            }
        }
        return;
    }

    // ---- flash attention role ----
    const int hh = bid >> 4;
    const int pi = bid & 15;                // 0..15
    const int lane = tid & 63, wave = tid >> 6;
    const int qt = (wave >> 2) ? (31 - pi) : pi;
    const int lr = lane & 15, lg = lane >> 4;
    const int q0 = qt * 64 + (wave & 3) * 16;
    const int myNT = qt + 1;
    const int NT   = 32 - pi;

    const int kr0 = tid >> 4, kc0 = (tid & 15) * 8;
    const int vr0 = tid >> 3, vc0 = (tid & 7) * 8;

    bf16x8 qf[4];
#pragma unroll
    for (int c = 0; c < 4; ++c)
        qf[c] = *reinterpret_cast<const bf16x8*>(
            q + (size_t)(q0 + lr) * 6144 + hh * 128 + c * 32 + lg * 8);

    f32x4 oacc[8] = {};
    float m_r[4], l_r[4];
#pragma unroll
    for (int r = 0; r < 4; ++r) { m_r[r] = -INFINITY; l_r[r] = 0.0f; }
    const float scale = 0.08838834764831845f;   // 1/sqrt(128)

    u16x8 kreg0, kreg1, vreg0, vreg1;
    auto gload = [&](int kt) {
        const int kv0 = kt * 64;
        kreg0 = *reinterpret_cast<const u16x8*>(k + (size_t)(kv0 + kr0) * 6144 + hh * 128 + kc0);
        kreg1 = *reinterpret_cast<const u16x8*>(k + (size_t)(kv0 + kr0 + 32) * 6144 + hh * 128 + kc0);
        vreg0 = *reinterpret_cast<const u16x8*>(vT + (size_t)(hh * 128 + vr0) * 2048 + kv0 + vc0);
        vreg1 = *reinterpret_cast<const u16x8*>(vT + (size_t)(hh * 128 + vr0 + 64) * 2048 + kv0 + vc0);
    };
    auto lwriteK = [&](int buf) {
        *reinterpret_cast<u16x8*>(&Ks[buf][kr0][kc0])      = kreg0;
        *reinterpret_cast<u16x8*>(&Ks[buf][kr0 + 32][kc0]) = kreg1;
    };
    auto lwriteV = [&]() {
        *reinterpret_cast<u16x8*>(&Vs[vr0][vc0])      = vreg0;
        *reinterpret_cast<u16x8*>(&Vs[vr0 + 64][vc0]) = vreg1;
    };

    gload(0);
    lwriteK(0);
    lwriteV();
    __syncthreads();

    for (int kt = 0; kt < NT; ++kt) {
        const int buf = kt & 1;
        if (kt + 1 < NT) gload(kt + 1);

        if (kt < myNT) {
            const int kv0 = kt * 64;
            const bool masked = (kt == myNT - 1);
            f32x4 s[4] = {};
            __builtin_amdgcn_s_setprio(1);
#pragma unroll
            for (int ct = 0; ct < 4; ++ct)
#pragma unroll
                for (int c = 0; c < 4; ++c) {
                    const bf16x8 kf = *reinterpret_cast<const bf16x8*>(
                        &Ks[buf][ct * 16 + lr][c * 32 + lg * 8]);
                    s[ct] = __builtin_amdgcn_mfma_f32_16x16x32_bf16(qf[c], kf, s[ct], 0, 0, 0);
                }
            __builtin_amdgcn_s_setprio(0);
#pragma unroll
            for (int ct = 0; ct < 4; ++ct)
#pragma unroll
                for (int r = 0; r < 4; ++r) {
                    float v = s[ct][r] * scale;
                    if (masked) {
                        const int kvg = kv0 + ct * 16 + lr;
                        const int qg  = q0 + lg * 4 + r;
                        if (kvg > qg) v = -INFINITY;
                    }
                    s[ct][r] = v;
                }
            // tile row-max
            float pmax[4];
#pragma unroll
            for (int r = 0; r < 4; ++r) {
                float v = fmaxf(fmaxf(s[0][r], s[1][r]), fmaxf(s[2][r], s[3][r]));
                v = fmaxf(v, __shfl_xor(v, 1));
                v = fmaxf(v, __shfl_xor(v, 2));
                v = fmaxf(v, __shfl_xor(v, 4));
                v = fmaxf(v, __shfl_xor(v, 8));
                pmax[r] = v;
            }
            // T13 defer-max: skip rescale when max growth <= 8 for all rows
            bool small = true;
#pragma unroll
            for (int r = 0; r < 4; ++r) small = small && (pmax[r] - m_r[r] <= 8.0f);
            if (!__all(small)) {
#pragma unroll
                for (int r = 0; r < 4; ++r) {
                    const float mn = fmaxf(m_r[r], pmax[r]);
                    const float alpha = __expf(m_r[r] - mn);
                    m_r[r] = mn;
                    l_r[r] *= alpha;
#pragma unroll
                    for (int ot = 0; ot < 8; ++ot) oacc[ot][r] *= alpha;
                }
            }
            float rs[4] = {0.f, 0.f, 0.f, 0.f};
#pragma unroll
            for (int ct = 0; ct < 4; ++ct)
#pragma unroll
                for (int r = 0; r < 4; ++r) {
                    const float p = __expf(s[ct][r] - m_r[r]);
                    s[ct][r] = p;
                    rs[r] += p;
                }
#pragma unroll
            for (int r = 0; r < 4; ++r) {
                float t2 = rs[r];
                t2 += __shfl_xor(t2, 1);
                t2 += __shfl_xor(t2, 2);
                t2 += __shfl_xor(t2, 4);
                t2 += __shfl_xor(t2, 8);
                l_r[r] += t2;
            }

#pragma unroll
            for (int ct = 0; ct < 4; ++ct)
#pragma unroll
                for (int r = 0; r < 4; ++r)
                    Ps[wave][lg * 4 + r][ct * 16 + lr] = f2bf(s[ct][r]);

            __builtin_amdgcn_s_setprio(1);
#pragma unroll
            for (int c2 = 0; c2 < 2; ++c2) {
                const bf16x8 pf = *reinterpret_cast<const bf16x8*>(
                    &Ps[wave][lr][c2 * 32 + lg * 8]);
#pragma unroll
                for (int ot = 0; ot < 8; ++ot) {
                    const bf16x8 vf = *reinterpret_cast<const bf16x8*>(
                        &Vs[ot * 16 + lr][c2 * 32 + lg * 8]);
                    oacc[ot] = __builtin_amdgcn_mfma_f32_16x16x32_bf16(pf, vf, oacc[ot], 0, 0, 0);
                }
            }
            __builtin_amdgcn_s_setprio(0);
        }

        if (kt + 1 < NT) lwriteK(buf ^ 1);
        __syncthreads();                 // PV(kt) reads done; K(kt+1) published
        if (kt + 1 < NT) lwriteV();
        __syncthreads();                 // V(kt+1) published
    }

#pragma unroll
    for (int ot = 0; ot < 8; ++ot)
#pragma unroll
        for (int r = 0; r < 4; ++r) {
            const float v = oacc[ot][r] / l_r[r];
            attn[(size_t)(q0 + lg * 4 + r) * 2048 + hh * 128 + ot * 16 + lr] = f2bf(v);
        }
}

// ---------------------------------------------------------------------------
extern "C" void kernel_launch(void* const* d_in, const int* in_sizes, int n_in,
                              void* d_out, int out_size, void* d_ws, size_t ws_size,
                              hipStream_t stream)
{
    const float* x    = (const float*)d_in[0];
    const float* fcos = (const float*)d_in[1];
    const float* fsin = (const float*)d_in[2];
    // d_in[3] = mask (causal, hardcoded)
    const float* wq  = (const float*)d_in[4];
    const float* wk  = (const float*)d_in[5];
    const float* wv  = (const float*)d_in[6];
    const float* wo  = (const float*)d_in[7];
    const float* w1  = (const float*)d_in[8];
    const float* w2  = (const float*)d_in[9];
    const float* w3  = (const float*)d_in[10];
    const float* anw = (const float*)d_in[11];
    const float* fnw = (const float*)d_in[12];
    float* out = (float*)d_out;

    char* ws = (char*)d_ws;
    size_t off = 0;
    auto alloc = [&](size_t bytes) { void* p = ws + off; off += bytes; return p; };
    const size_t SZ_DD = (size_t)2048 * 2048 * 2;   // 8 MiB
    const size_t SZ_DF = (size_t)2048 * 5632 * 2;   // 22 MiB

    unsigned short* qkvoT = (unsigned short*)alloc(4 * SZ_DD);  // wq|wk|wv|wo T
    unsigned short* w13T  = (unsigned short*)alloc(2 * SZ_DF);  // interleaved [11264][2048]
    unsigned short* w2T   = (unsigned short*)alloc(SZ_DF);

    char* reg1 = (char*)alloc((size_t)48 * 1024 * 1024);
    unsigned short* xn   = (unsigned short*)reg1;
    unsigned short* qkv  = (unsigned short*)(reg1 + SZ_DD);            // [2048][6144]
    unsigned short* vTb  = (unsigned short*)(reg1 + SZ_DD + 3 * SZ_DD);
    unsigned short* ab   = (unsigned short*)(reg1 + SZ_DD + 4 * SZ_DD);
    float*          pk   = (float*)reg1;                               // [2][2048][2048] f32
    unsigned short* hn   = (unsigned short*)(reg1 + 4 * SZ_DD);        // [2048][2048]

    char* reg2 = (char*)alloc(SZ_DF);
    unsigned short* t1 = (unsigned short*)reg2;                        // [2048][5632]

    // rmsnorm(x) + wq/wk/wv fp32->bf16 transposed, merged
    prep_kernel<<<5120, 256, 0, stream>>>(x, anw, xn, wq, wk, wv, qkvoT);

    // fused QKV + RoPE + V-transpose (384 blocks)
    gemm128d<4><<<dim3(24, 16), 512, 0, stream>>>(xn, qkvoT, qkv, nullptr,
                                                  2048, 6144, 2048, fcos, fsin, vTb);
    // flash attention (defer-max) + co-resident convT for wo / {w1,w3} / w2
    flash_mega<<<768, 512, 0, stream>>>(qkv, qkv + 2048, vTb, ab,
                                        wo, w1, w3, w2,
                                        qkvoT + 3 * (size_t)2048 * 2048, w13T, w2T);
    // Wo split-K=2
    gemm128d<1><<<dim3(8, 16, 2), 512, 0, stream>>>(ab, qkvoT + 3 * (size_t)2048 * 2048,
                                                    nullptr, pk, 2048, 2048, 2048,
                                                    nullptr, nullptr, nullptr);
    // fused: out = x + Wo-partials; hn = rmsnorm(out) * fnw
    reduce2_norm<<<2048, 256, 0, stream>>>(x, pk, fnw, out, hn);

    // W13 + fused SwiGLU epilogue: t1 = silu(hn@w1) * (hn@w3), 704 blocks
    gemm128d<2><<<dim3(44, 16), 512, 0, stream>>>(hn, w13T, t1, nullptr,
                                                  2048, 11264, 2048,
                                                  nullptr, nullptr, nullptr);
    // W2 split-K=2 with atomic residual add into out (out already holds h)
    gemm128d<3><<<dim3(8, 16, 2), 512, 0, stream>>>(t1, w2T, nullptr, out,
                                                    2048, 2048, 5632,
                                                    nullptr, nullptr, nullptr);
}